// Round 1
// 264.939 us; speedup vs baseline: 1.0194x; 1.0194x over previous
//
#include <hip/hip_runtime.h>

#define NTOK 4096          // N
#define EDIM 128

typedef __attribute__((ext_vector_type(8))) short bf16x8;
typedef __attribute__((ext_vector_type(4))) float f32x4;

__device__ __forceinline__ ushort f2bf(float x) {
    union { float f; unsigned u; } c; c.f = x;
    unsigned r = c.u + 0x7FFF + ((c.u >> 16) & 1);
    return (ushort)(r >> 16);
}

// stage a 128x128 fp32 weight (row-major) into bf16 LDS tile [128][136]
__device__ __forceinline__ void stage_w(const float* __restrict__ W, ushort* Bs) {
    const int t = threadIdx.x;
    const int br = t >> 1, h = (t & 1) * 64;
    const float* src = W + (size_t)br * 128 + h;
    ushort* dst = Bs + br * 136 + h;
#pragma unroll
    for (int j = 0; j < 8; ++j) {
        float4 u = *(const float4*)(src + j * 8);
        float4 v = *(const float4*)(src + j * 8 + 4);
        bf16x8 o;
        o[0] = (short)f2bf(u.x); o[1] = (short)f2bf(u.y);
        o[2] = (short)f2bf(u.z); o[3] = (short)f2bf(u.w);
        o[4] = (short)f2bf(v.x); o[5] = (short)f2bf(v.y);
        o[6] = (short)f2bf(v.z); o[7] = (short)f2bf(v.w);
        *(bf16x8*)(dst + j * 8) = o;
    }
}

// 32x128 x K=128 bf16 MFMA GEMM from LDS tiles (As[32][136], Bs[128][136])
__device__ __forceinline__ void gemm128(const ushort* __restrict__ As,
                                        const ushort* __restrict__ Bs,
                                        f32x4 (&acc)[2][2], int lane, int wv) {
    const int m15 = lane & 15, kq = (lane >> 4) * 8, c0w = wv * 32;
#pragma unroll
    for (int kc = 0; kc < 4; ++kc) {
        int ko = kc * 32 + kq;
        bf16x8 a0 = *(const bf16x8*)&As[m15 * 136 + ko];
        bf16x8 a1 = *(const bf16x8*)&As[(16 + m15) * 136 + ko];
        bf16x8 b0 = *(const bf16x8*)&Bs[(c0w + m15) * 136 + ko];
        bf16x8 b1 = *(const bf16x8*)&Bs[(c0w + 16 + m15) * 136 + ko];
        acc[0][0] = __builtin_amdgcn_mfma_f32_16x16x32_bf16(a0, b0, acc[0][0], 0, 0, 0);
        acc[0][1] = __builtin_amdgcn_mfma_f32_16x16x32_bf16(a0, b1, acc[0][1], 0, 0, 0);
        acc[1][0] = __builtin_amdgcn_mfma_f32_16x16x32_bf16(a1, b0, acc[1][0], 0, 0, 0);
        acc[1][1] = __builtin_amdgcn_mfma_f32_16x16x32_bf16(a1, b1, acc[1][1], 0, 0, 0);
    }
}

// ---------------------------------------------------------------------------
// K1: blocks [0,256): per-32-row fused rms1 + Q/K/V GEMMs -> sigq, Mt.
//     blocks [256,400): Wcomb/W1/W2 fp32->bf16 for the tail kernel.
// ---------------------------------------------------------------------------
__launch_bounds__(256, 2)
__global__ void qkv_k(const float* __restrict__ input1, const float* __restrict__ ln1w,
                      const float* __restrict__ Wq, const float* __restrict__ Wk,
                      const float* __restrict__ Wv,
                      const float* __restrict__ Wc, const float* __restrict__ W1,
                      const float* __restrict__ W2, ushort* __restrict__ Wbf,
                      float* __restrict__ sigq, ushort* __restrict__ Mt) {
    const int bx = blockIdx.x;
    if (bx >= 256) {                       // weight conversion (147456 f32)
        int g = ((bx - 256) * 256 + threadIdx.x) * 4;
        const float* src; ushort* dst;
        if (g < 16384)      { src = Wc + g;           dst = Wbf + 49152 + g; }
        else if (g < 81920) { src = W1 + (g - 16384); dst = Wbf + 65536 + (g - 16384); }
        else                { src = W2 + (g - 81920); dst = Wbf + 131072 + (g - 81920); }
        float4 u = *(const float4*)src;
        ushort4 o; o.x = f2bf(u.x); o.y = f2bf(u.y); o.z = f2bf(u.z); o.w = f2bf(u.w);
        *(ushort4*)dst = o;
        return;
    }
    __shared__ ushort As[32 * 136];
    __shared__ ushort Bs0[128 * 136];
    __shared__ ushort Bs1[128 * 136];
    const int t = threadIdx.x, lane = t & 63, wv = t >> 6;
    const int m15 = lane & 15, quad = lane >> 4, c0w = wv * 32;
    const int M0 = bx * 32;

    // rms1: h = rmsnorm(input1 rows, ln1) -> As (bf16)
    {
        const int row = t >> 3, seg = t & 7;
        const float* xp = input1 + (size_t)(M0 + row) * 128 + seg * 16;
        float4 x[4]; float ss = 0.f;
#pragma unroll
        for (int i = 0; i < 4; ++i) {
            x[i] = *(const float4*)(xp + i * 4);
            ss += x[i].x * x[i].x + x[i].y * x[i].y + x[i].z * x[i].z + x[i].w * x[i].w;
        }
        ss += __shfl_down(ss, 4, 8);
        ss += __shfl_down(ss, 2, 8);
        ss += __shfl_down(ss, 1, 8);
        ss = __shfl(ss, 0, 8);
        float rr = rsqrtf(ss * (1.0f / 128.0f) + 1e-6f);
#pragma unroll
        for (int i = 0; i < 4; ++i) {
            float4 w4 = *(const float4*)&ln1w[seg * 16 + i * 4];
            ushort4 o;
            o.x = f2bf(x[i].x * rr * w4.x);
            o.y = f2bf(x[i].y * rr * w4.y);
            o.z = f2bf(x[i].z * rr * w4.z);
            o.w = f2bf(x[i].w * rr * w4.w);
            *(ushort4*)&As[row * 136 + seg * 16 + i * 4] = o;
        }
    }
    stage_w(Wq, Bs0);
    __syncthreads();
    {   // GEMM q -> sigmoid -> sigq ; overlap Wk staging into Bs1
        f32x4 acc[2][2] = {};
        gemm128(As, Bs0, acc, lane, wv);
        stage_w(Wk, Bs1);
#pragma unroll
        for (int mi = 0; mi < 2; ++mi)
#pragma unroll
            for (int ni = 0; ni < 2; ++ni)
#pragma unroll
                for (int r = 0; r < 4; ++r) {
                    int row = M0 + mi * 16 + quad * 4 + r;
                    int lc  = c0w + ni * 16 + m15;
                    sigq[(size_t)row * 128 + lc] = 1.0f / (1.0f + __expf(-acc[mi][ni][r]));
                }
    }
    __syncthreads();
    f32x4 acck[2][2] = {};
    gemm128(As, Bs1, acck, lane, wv);
    stage_w(Wv, Bs0);                     // Bs0 free: all q-reads done at last barrier
    __syncthreads();
    f32x4 accv[2][2] = {};
    gemm128(As, Bs0, accv, lane, wv);
    // Mt epilogue: Mt[b][e][i]=exp(k)*v, Mt[b][128+e][i]=exp(k)
    const int b = M0 >> 12, i0 = M0 & (NTOK - 1);
#pragma unroll
    for (int mi = 0; mi < 2; ++mi)
#pragma unroll
        for (int ni = 0; ni < 2; ++ni) {
            int e = c0w + ni * 16 + m15;
            ushort* mt0 = Mt + ((size_t)b * 256 + e) * NTOK;
            ushort* mt1 = mt0 + (size_t)128 * NTOK;
            int ib = i0 + mi * 16 + quad * 4;
            ushort4 pv, pk;
            float kw0 = __expf(acck[mi][ni][0]); pv.x = f2bf(kw0 * accv[mi][ni][0]); pk.x = f2bf(kw0);
            float kw1 = __expf(acck[mi][ni][1]); pv.y = f2bf(kw1 * accv[mi][ni][1]); pk.y = f2bf(kw1);
            float kw2 = __expf(acck[mi][ni][2]); pv.z = f2bf(kw2 * accv[mi][ni][2]); pk.z = f2bf(kw2);
            float kw3 = __expf(acck[mi][ni][3]); pv.w = f2bf(kw3 * accv[mi][ni][3]); pk.w = f2bf(kw3);
            *(ushort4*)&mt0[ib] = pv;
            *(ushort4*)&mt1[ib] = pk;
        }
}

// ---------------------------------------------------------------------------
// K2: P[b,j,c] = sum_i exp(coef*dis[b,j,i]) * Mt[b,c,i]
// 64j x 256c tile, BK=64, K-split 2. 512 thr (8 waves, each 64j x 32c).
// B (Mt) loaded DIRECTLY global->reg (one consumer wave per row -> no LDS
// round-trip); only exp'd A goes through LDS. A prefetch depth 2 (HBM),
// B depth 1 (L2). XCD-quadrant swizzle: blocks of one (b,s) share 2 XCDs.
// ---------------------------------------------------------------------------
__launch_bounds__(512, 2)
__global__ void big_gemm_k(const float* __restrict__ dis, const float* __restrict__ alphap,
                           const ushort* __restrict__ Mt,
                           float* __restrict__ P0, float* __restrict__ P1) {
    __shared__ ushort As[64 * 72];
    const int P = blockIdx.x;
    const int q = (P & 7) >> 1;                 // quadrant (b,s) -> XCDs {2q,2q+1}
    const int b = q & 1, s = q >> 1;
    const int j0 = (((P >> 3) << 1) | (P & 1)) * 64;
    const int t = threadIdx.x, lane = t & 63, wv = t >> 6;
    const int m15 = lane & 15, quad = lane >> 4, kq = quad * 8;
    const float coef = -alphap[0] * 12.0f;      // log2(4096) = 12
    const float* disb = dis + (size_t)b * NTOK * NTOK;
    const ushort* Mtb = Mt + (size_t)b * 256 * NTOK;
    float* outp = ((s == 0) ? P0 : P1) + (size_t)b * NTOK * 256;
    const int k0 = s * (NTOK / 2);

    const int aj = t >> 3, ak = (t & 7) * 8;
    const float* arow = disb + (size_t)(j0 + aj) * NTOK;
    const int c0 = wv * 32;
    const ushort* Bp = Mtb + (size_t)(c0 + m15) * NTOK + kq;

    f32x4 acc[4][2] = {};
    float4 fA0, fA1, fB0, fB1;
    bf16x8 pb[2][2], pbn[2][2];
    fA0 = *(const float4*)(arow + k0 + ak);
    fA1 = *(const float4*)(arow + k0 + ak + 4);
    fB0 = *(const float4*)(arow + k0 + 64 + ak);
    fB1 = *(const float4*)(arow + k0 + 64 + ak + 4);
#pragma unroll
    for (int kh = 0; kh < 2; ++kh)
#pragma unroll
        for (int ni = 0; ni < 2; ++ni)
            pb[kh][ni] = *(const bf16x8*)&Bp[(size_t)(ni * 16) * NTOK + k0 + kh * 32];

#define BIG_ITER(FA0, FA1, PBC, PBN, IT) do {                                   \
    bf16x8 a8;                                                                  \
    a8[0] = (short)f2bf(__expf(coef * FA0.x));                                  \
    a8[1] = (short)f2bf(__expf(coef * FA0.y));                                  \
    a8[2] = (short)f2bf(__expf(coef * FA0.z));                                  \
    a8[3] = (short)f2bf(__expf(coef * FA0.w));                                  \
    a8[4] = (short)f2bf(__expf(coef * FA1.x));                                  \
    a8[5] = (short)f2bf(__expf(coef * FA1.y));                                  \
    a8[6] = (short)f2bf(__expf(coef * FA1.z));                                  \
    a8[7] = (short)f2bf(__expf(coef * FA1.w));                                  \
    *(bf16x8*)&As[aj * 72 + ak] = a8;                                           \
    __syncthreads();                                                            \
    {   int itA = (IT) + 2; int ka = (itA < 32) ? k0 + itA * 64 : k0;           \
        FA0 = *(const float4*)(arow + ka + ak);                                 \
        FA1 = *(const float4*)(arow + ka + ak + 4);                             \
        int itB = (IT) + 1; int kb_ = (itB < 32) ? k0 + itB * 64 : k0;          \
        _Pragma("unroll") for (int kh = 0; kh < 2; ++kh)                        \
        _Pragma("unroll") for (int ni = 0; ni < 2; ++ni)                        \
            PBN[kh][ni] = *(const bf16x8*)&Bp[(size_t)(ni * 16) * NTOK + kb_ + kh * 32]; } \
    _Pragma("unroll") for (int kh = 0; kh < 2; ++kh) {                          \
        bf16x8 av0 = *(const bf16x8*)&As[(m15) * 72 + kh * 32 + kq];            \
        bf16x8 av1 = *(const bf16x8*)&As[(16 + m15) * 72 + kh * 32 + kq];       \
        bf16x8 av2 = *(const bf16x8*)&As[(32 + m15) * 72 + kh * 32 + kq];       \
        bf16x8 av3 = *(const bf16x8*)&As[(48 + m15) * 72 + kh * 32 + kq];       \
        acc[0][0] = __builtin_amdgcn_mfma_f32_16x16x32_bf16(av0, PBC[kh][0], acc[0][0], 0, 0, 0); \
        acc[0][1] = __builtin_amdgcn_mfma_f32_16x16x32_bf16(av0, PBC[kh][1], acc[0][1], 0, 0, 0); \
        acc[1][0] = __builtin_amdgcn_mfma_f32_16x16x32_bf16(av1, PBC[kh][0], acc[1][0], 0, 0, 0); \
        acc[1][1] = __builtin_amdgcn_mfma_f32_16x16x32_bf16(av1, PBC[kh][1], acc[1][1], 0, 0, 0); \
        acc[2][0] = __builtin_amdgcn_mfma_f32_16x16x32_bf16(av2, PBC[kh][0], acc[2][0], 0, 0, 0); \
        acc[2][1] = __builtin_amdgcn_mfma_f32_16x16x32_bf16(av2, PBC[kh][1], acc[2][1], 0, 0, 0); \
        acc[3][0] = __builtin_amdgcn_mfma_f32_16x16x32_bf16(av3, PBC[kh][0], acc[3][0], 0, 0, 0); \
        acc[3][1] = __builtin_amdgcn_mfma_f32_16x16x32_bf16(av3, PBC[kh][1], acc[3][1], 0, 0, 0); \
    }                                                                           \
    __syncthreads();                                                            \
} while (0)

    for (int it2 = 0; it2 < 16; ++it2) {
        BIG_ITER(fA0, fA1, pb, pbn, it2 * 2);
        BIG_ITER(fB0, fB1, pbn, pb, it2 * 2 + 1);
    }
#undef BIG_ITER

#pragma unroll
    for (int mi = 0; mi < 4; ++mi)
#pragma unroll
        for (int ni = 0; ni < 2; ++ni)
#pragma unroll
            for (int r = 0; r < 4; ++r) {
                int j = j0 + mi * 16 + quad * 4 + r;
                int c = c0 + ni * 16 + m15;
                outp[(size_t)j * 256 + c] = acc[mi][ni][r];
            }
}

// ---------------------------------------------------------------------------
// K3: per-32-row block: attn=sigq*(w1/w2) -> GEMM Wcomb -> +input1 (out1 in
// LDS) -> rms2 (h2 in LDS) -> FFN1/FFN2 in 4 F-chunks -> out = out1+b2+ffn.
// h2, mid, outD never touch global memory.
// ---------------------------------------------------------------------------
__launch_bounds__(256, 1)
__global__ void tail_k(const float* __restrict__ sigq,
                       const float* __restrict__ P0, const float* __restrict__ P1,
                       const ushort* __restrict__ Wbf,
                       const float* __restrict__ input1, const float* __restrict__ b1,
                       const float* __restrict__ b2, const float* __restrict__ ln2w,
                       float* __restrict__ out) {
    __shared__ ushort As[32 * 136];       // attn A, then h2
    __shared__ ushort As2[32 * 136];      // mid chunk
    __shared__ ushort Bs[128 * 136];      // Wcomb, then W1 chunk
    __shared__ ushort Bs2[128 * 136];     // W2 chunk
    __shared__ float  O[32][132];         // out1
    const int t = threadIdx.x, lane = t & 63, wv = t >> 6;
    const int m15 = lane & 15, quad = lane >> 4, c0w = wv * 32;
    const int M0 = blockIdx.x * 32;

    // A staging: attn[g,e] = sigq * (P0+P1 top)/(P0+P1 bottom)
    {
        const int ar = t >> 3, e0 = (t & 7) * 16;
        const int g = M0 + ar;
        const float4* sg  = (const float4*)(sigq + (size_t)g * 128 + e0);
        const float4* p0a = (const float4*)(P0 + (size_t)g * 256 + e0);
        const float4* p1a = (const float4*)(P1 + (size_t)g * 256 + e0);
        const float4* p0b = (const float4*)(P0 + (size_t)g * 256 + 128 + e0);
        const float4* p1b = (const float4*)(P1 + (size_t)g * 256 + 128 + e0);
#pragma unroll
        for (int i = 0; i < 4; ++i) {
            float4 s = sg[i];
            float4 u0 = p0a[i], u1 = p1a[i], d0 = p0b[i], d1 = p1b[i];
            ushort4 a;
            a.x = f2bf(s.x * (u0.x + u1.x) / (d0.x + d1.x));
            a.y = f2bf(s.y * (u0.y + u1.y) / (d0.y + d1.y));
            a.z = f2bf(s.z * (u0.z + u1.z) / (d0.z + d1.z));
            a.w = f2bf(s.w * (u0.w + u1.w) / (d0.w + d1.w));
            *(ushort4*)&As[ar * 136 + e0 + i * 4] = a;
        }
    }
    {   // B staging: Wcomb (bf16)
        const int br = t >> 1, bs0 = (t & 1) * 8;
        const ushort* W = Wbf + 49152;
#pragma unroll
        for (int j = 0; j < 8; ++j) {
            int seg = bs0 + j;
            *(bf16x8*)&Bs[br * 136 + seg * 8] = *(const bf16x8*)&W[(size_t)br * 128 + seg * 8];
        }
    }
    __syncthreads();
    f32x4 acc[2][2] = {};
    gemm128(As, Bs, acc, lane, wv);
    // epilogue 1: out1 = acc + input1 -> LDS O
#pragma unroll
    for (int mi = 0; mi < 2; ++mi)
#pragma unroll
        for (int ni = 0; ni < 2; ++ni)
#pragma unroll
            for (int r = 0; r < 4; ++r) {
                int rl  = mi * 16 + quad * 4 + r;
                int col = c0w + ni * 16 + m15;
                O[rl][col] = acc[mi][ni][r] + input1[(size_t)(M0 + rl) * 128 + col];
            }
    __syncthreads();
    // rms2: h2 = rmsnorm(out1, ln2) -> As (bf16). As is dead (GEMM done).
    {
        const int row = t >> 3, seg = t & 7;
        float4 x[4]; float ss = 0.f;
#pragma unroll
        for (int i = 0; i < 4; ++i) {
            x[i] = *(const float4*)&O[row][seg * 16 + i * 4];
            ss += x[i].x * x[i].x + x[i].y * x[i].y + x[i].z * x[i].z + x[i].w * x[i].w;
        }
        ss += __shfl_down(ss, 4, 8);
        ss += __shfl_down(ss, 2, 8);
        ss += __shfl_down(ss, 1, 8);
        ss = __shfl(ss, 0, 8);
        float rr = rsqrtf(ss * (1.0f / 128.0f) + 1e-6f);
#pragma unroll
        for (int i = 0; i < 4; ++i) {
            float4 w4 = *(const float4*)&ln2w[seg * 16 + i * 4];
            ushort4 o;
            o.x = f2bf(x[i].x * rr * w4.x);
            o.y = f2bf(x[i].y * rr * w4.y);
            o.z = f2bf(x[i].z * rr * w4.z);
            o.w = f2bf(x[i].w * rr * w4.w);
            *(ushort4*)&As[row * 136 + seg * 16 + i * 4] = o;
        }
    }
    // FFN in 4 chunks of F=128
    f32x4 aout[2][2] = {};
    for (int f0 = 0; f0 < 4; ++f0) {
        __syncthreads();   // prior GEMM reads of Bs/Bs2/As2 done; h2 write visible
        {   // stage W1 chunk (ldb 128) and W2 chunk (ldb 512)
            const int br = t >> 1, h = (t & 1) * 64;
            const ushort* w1 = Wbf + 65536 + (size_t)(f0 * 128 + br) * 128 + h;
            const ushort* w2 = Wbf + 131072 + (size_t)br * 512 + f0 * 128 + h;
            ushort* d1 = Bs + br * 136 + h;
            ushort* d2 = Bs2 + br * 136 + h;
#pragma unroll
            for (int j = 0; j < 8; ++j) {
                *(bf16x8*)(d1 + j * 8) = *(const bf16x8*)(w1 + j * 8);
                *(bf16x8*)(d2 + j * 8) = *(const bf16x8*)(w2 + j * 8);
            }
        }
        __syncthreads();
        f32x4 am[2][2] = {};
        gemm128(As, Bs, am, lane, wv);
        // mid = relu(am + b1) -> As2 (bf16)
#pragma unroll
        for (int mi = 0; mi < 2; ++mi)
#pragma unroll
            for (int ni = 0; ni < 2; ++ni)
#pragma unroll
                for (int r = 0; r < 4; ++r) {
                    int rl  = mi * 16 + quad * 4 + r;
                    int col = c0w + ni * 16 + m15;
                    As2[rl * 136 + col] = f2bf(fmaxf(am[mi][ni][r] + b1[f0 * 128 + col], 0.0f));
                }
        __syncthreads();
        gemm128(As2, Bs2, aout, lane, wv);
    }
    // final: out = out1 + b2 + ffn
#pragma unroll
    for (int mi = 0; mi < 2; ++mi)
#pragma unroll
        for (int ni = 0; ni < 2; ++ni)
#pragma unroll
            for (int r = 0; r < 4; ++r) {
                int rl  = mi * 16 + quad * 4 + r;
                int col = c0w + ni * 16 + m15;
                out[(size_t)(M0 + rl) * 128 + col] = (O[rl][col] + b2[col]) + aout[mi][ni][r];
            }
}

// ---------------------------------------------------------------------------
extern "C" void kernel_launch(void* const* d_in, const int* in_sizes, int n_in,
                              void* d_out, int out_size, void* d_ws, size_t ws_size,
                              hipStream_t stream) {
    const float* input1 = (const float*)d_in[0];
    const float* dis    = (const float*)d_in[1];
    const float* Wq     = (const float*)d_in[2];
    const float* Wk     = (const float*)d_in[3];
    const float* Wv     = (const float*)d_in[4];
    const float* alpha  = (const float*)d_in[5];
    const float* ln1    = (const float*)d_in[6];
    const float* ln2    = (const float*)d_in[7];
    const float* Wcomb  = (const float*)d_in[8];
    const float* W1     = (const float*)d_in[9];
    const float* b1     = (const float*)d_in[10];
    const float* W2     = (const float*)d_in[11];
    const float* b2     = (const float*)d_in[12];
    float* out = (float*)d_out;

    // workspace overlay (peak 28 MiB)
    char* w8 = (char*)d_ws;
    ushort* Wbf  = (ushort*)(w8);                  // [0,384K)  Wcomb/W1/W2 bf16
    float*  sigq = (float*)(w8 + (4u << 20));      // [4,8M)
    ushort* Mt   = (ushort*)(w8 + (8u << 20));     // [8,12M)
    float*  P0   = (float*)(w8 + (12u << 20));     // [12,20M)
    float*  P1   = (float*)(w8 + (20u << 20));     // [20,28M)

    // 1) fused rms1 + Q/K/V (+ weight conversion for tail)
    qkv_k<<<dim3(400), 256, 0, stream>>>(input1, ln1, Wq, Wk, Wv,
                                         Wcomb, W1, W2, Wbf, sigq, Mt);
    // 2) big GEMM, K-split 2, B direct-to-reg, depth-2 prefetch
    big_gemm_k<<<dim3(256), 512, 0, stream>>>(dis, alpha, Mt, P0, P1);
    // 3) attn + Wcomb + residual + rms2 + FFN1 + FFN2 -> out
    tail_k<<<dim3(256), 256, 0, stream>>>(sigq, P0, P1, Wbf, input1, b1, b2,
                                          ln2, out);
}